// Round 6
// baseline (1778.984 us; speedup 1.0000x reference)
//
#include <hip/hip_runtime.h>
#include <math.h>

#define N_ 8
#define C_ 64
#define T_ 12
#define V_ 400
#define D_ 768
#define HE_ 14
#define HN_ 96
#define VV 160000          // V*V
#define NVD 2457600        // N*V*D
#define NVH 307200         // N*V*HN
#define NVV 1280000        // N*V*V

// ---------------------------------------------------------------------------
// Transpose x [8,768,400] -> xT [8,400,768]   (d = c*T + t)
// ---------------------------------------------------------------------------
__global__ __launch_bounds__(256) void transpose_x_kernel(
    const float* __restrict__ x, float* __restrict__ xT)
{
    __shared__ float tile[32][33];
    int n  = blockIdx.z;
    int d0 = blockIdx.y * 32;
    int v0 = blockIdx.x * 32;
    int tx = threadIdx.x & 31, ty = threadIdx.x >> 5;
#pragma unroll
    for (int r = 0; r < 4; r++) {
        int d = d0 + ty + r * 8;
        int v = v0 + tx;
        float val = (v < V_) ? x[((long)n * D_ + d) * V_ + v] : 0.f;
        tile[ty + r * 8][tx] = val;
    }
    __syncthreads();
#pragma unroll
    for (int r = 0; r < 4; r++) {
        int v = v0 + ty + r * 8;
        int d = d0 + tx;
        if (v < V_) xT[((long)n * V_ + v) * D_ + d] = tile[tx][ty + r * 8];
    }
}

// ---------------------------------------------------------------------------
// Edge MLP: A[8,8,400,400] -> A_new[8,64,400,400] (masked) + A_s[8,400,400]
// ---------------------------------------------------------------------------
__global__ __launch_bounds__(256) void edge_mlp_kernel(
    const float* __restrict__ A,
    const float* __restrict__ We1, const float* __restrict__ be1,
    const float* __restrict__ We2, const float* __restrict__ be2,
    const float* __restrict__ We3, const float* __restrict__ be3,
    float* __restrict__ A_new, float* __restrict__ A_s)
{
    __shared__ float w1[7 * 14], b1[14], w2[14 * 14], b2[14], w3[14 * 64], b3[64];
    int tid = threadIdx.x;
    for (int i = tid; i < 98;  i += 256) w1[i] = We1[i];
    for (int i = tid; i < 196; i += 256) w2[i] = We2[i];
    for (int i = tid; i < 896; i += 256) w3[i] = We3[i];
    for (int i = tid; i < 14;  i += 256) { b1[i] = be1[i]; b2[i] = be2[i]; }
    for (int i = tid; i < 64;  i += 256) b3[i] = be3[i];
    __syncthreads();

    int j = blockIdx.x * 256 + tid;
    if (j >= V_) return;
    int i_ = blockIdx.y;
    int n  = blockIdx.z;

    long base = ((long)(n * 8) * V_ + i_) * V_ + j;
    float feat[7];
#pragma unroll
    for (int k = 0; k < 7; k++) feat[k] = A[base + (long)k * VV];
    float mk = (A[base + 7L * VV] > 0.5f) ? 1.0f : 0.0f;

    float e1[14];
#pragma unroll
    for (int l = 0; l < 14; l++) {
        float s = b1[l];
#pragma unroll
        for (int k = 0; k < 7; k++) s = fmaf(feat[k], w1[k * 14 + l], s);
        e1[l] = fmaxf(s, 0.f);
    }
    float e2[14];
#pragma unroll
    for (int l = 0; l < 14; l++) {
        float s = b2[l];
#pragma unroll
        for (int k = 0; k < 14; k++) s = fmaf(e1[k], w2[k * 14 + l], s);
        e2[l] = fmaxf(s, 0.f);
    }

    long obase = ((long)(n * C_) * V_ + i_) * V_ + j;
    float sum = 0.f;
#pragma unroll
    for (int c = 0; c < 64; c++) {
        float s = b3[c];
#pragma unroll
        for (int l = 0; l < 14; l++) s = fmaf(e2[l], w3[l * 64 + c], s);
        s *= mk;
        A_new[obase + (long)c * VV] = s;
        sum += s;
    }
    A_s[((long)n * V_ + i_) * V_ + j] = sum * (1.0f / 64.0f);
}

// ---------------------------------------------------------------------------
// Generic tiled fp32 GEMM: C = act( A1@B1 [+ A2@B2] [+ addmat] + bias ).
// BM=128, BN=64, BK=16, 256 threads, 8x4 per thread.
// ACT: 0 none, 1 relu, 2 sigmoid, 3 sigmoid*aux1,
//      4 GRU update: tanh(acc + addmat) blended with aux1=zg, aux2=h
//      5 gate-triple (batch offsets must be 0):
//         z==0: sigmoid(m@Wz + h@Uz + bz)          -> Cmat
//         z==1: sigmoid(m@Wr + h@Ur + br)*aux1     -> Cr   (B1r/B2r/biasr)
//         z==2: m@Wh + bh (single phase)           -> Ch   (B1h/biash)
// ---------------------------------------------------------------------------
template <int ACT, bool DUAL>
__global__ __launch_bounds__(256) void gemm_kernel(
    const float* __restrict__ A1, int lda1, const float* __restrict__ B1, int ldb1, int K1,
    const float* __restrict__ A2, int lda2, const float* __restrict__ B2, int ldb2, int K2,
    const float* __restrict__ bias, float* __restrict__ Cmat, int ldc,
    const float* __restrict__ aux1, const float* __restrict__ aux2,
    int M, int Ncols, long batchA, long batchB, long batchC,
    const float* __restrict__ B1r, const float* __restrict__ B2r,
    const float* __restrict__ biasr, float* __restrict__ Cr,
    const float* __restrict__ B1h, const float* __restrict__ biash,
    float* __restrict__ Ch, const float* __restrict__ addmat)
{
    __shared__ float As[16][132];
    __shared__ float Bs[16][68];
    const int tid = threadIdx.x;
    const int tx = tid & 15;
    const int ty = tid >> 4;
    const int row0 = blockIdx.x * 128;
    const int col0 = blockIdx.y * 64;
    const int bz = blockIdx.z;

    if (ACT == 5) {                      // gate-triple selector (batches are 0)
        if (bz == 1)      { B1 = B1r; B2 = B2r;     bias = biasr; Cmat = Cr; }
        else if (bz == 2) { B1 = B1h; B2 = nullptr; bias = biash; Cmat = Ch; }
    }

    A1 += (long)bz * batchA;
    B1 += (long)bz * batchB;
    Cmat += (long)bz * batchC;
    const float* A2b = DUAL ? A2 + (long)bz * batchA : nullptr;
    const float* B2b = (DUAL && B2) ? B2 + (long)bz * batchB : nullptr;

    float acc[8][4];
#pragma unroll
    for (int i = 0; i < 8; i++)
#pragma unroll
        for (int j = 0; j < 4; j++) acc[i][j] = 0.f;

    const int nphase = (ACT == 5 && bz == 2) ? 1 : (DUAL ? 2 : 1);
#pragma unroll 1
    for (int phase = 0; phase < nphase; phase++) {
        const float* Ap = phase ? A2b : A1;
        const float* Bp = phase ? B2b : B1;
        const int lda = phase ? lda2 : lda1;
        const int ldb = phase ? ldb2 : ldb1;
        const int K   = phase ? K2 : K1;
        for (int k0 = 0; k0 < K; k0 += 16) {
#pragma unroll
            for (int l = 0; l < 2; l++) {
                int idx = tid + l * 256;   // float4 units of the 128x16 A tile
                int row = idx >> 2;
                int kk  = (idx & 3) * 4;
                float4 v = make_float4(0.f, 0.f, 0.f, 0.f);
                if (row0 + row < M)
                    v = *reinterpret_cast<const float4*>(Ap + (long)(row0 + row) * lda + k0 + kk);
                As[kk + 0][row] = v.x;
                As[kk + 1][row] = v.y;
                As[kk + 2][row] = v.z;
                As[kk + 3][row] = v.w;
            }
            {
                int k  = tid >> 4;
                int nn = (tid & 15) * 4;
                float4 v = make_float4(0.f, 0.f, 0.f, 0.f);
                if (col0 + nn < Ncols)
                    v = *reinterpret_cast<const float4*>(Bp + (long)(k0 + k) * ldb + col0 + nn);
                *reinterpret_cast<float4*>(&Bs[k][nn]) = v;
            }
            __syncthreads();
#pragma unroll
            for (int kk = 0; kk < 16; kk++) {
                float4 a0 = *reinterpret_cast<const float4*>(&As[kk][ty * 4]);
                float4 a1 = *reinterpret_cast<const float4*>(&As[kk][ty * 4 + 64]);
                float4 b0 = *reinterpret_cast<const float4*>(&Bs[kk][tx * 4]);
                float a[8] = {a0.x, a0.y, a0.z, a0.w, a1.x, a1.y, a1.z, a1.w};
                float b[4] = {b0.x, b0.y, b0.z, b0.w};
#pragma unroll
                for (int i = 0; i < 8; i++)
#pragma unroll
                    for (int j = 0; j < 4; j++)
                        acc[i][j] = fmaf(a[i], b[j], acc[i][j]);
            }
            __syncthreads();
        }
    }

#pragma unroll
    for (int i = 0; i < 8; i++) {
        int r = row0 + ((i < 4) ? (ty * 4 + i) : (64 + ty * 4 + i - 4));
        if (r >= M) continue;
#pragma unroll
        for (int j = 0; j < 4; j++) {
            int c = col0 + tx * 4 + j;
            if (c >= Ncols) continue;
            float s = acc[i][j];
            if (bias) s += bias[c];
            long idx = (long)r * ldc + c;
            if (ACT == 0) {
                Cmat[idx] = s;
            } else if (ACT == 1) {
                Cmat[idx] = fmaxf(s, 0.f);
            } else if (ACT == 2) {
                Cmat[idx] = 1.f / (1.f + expf(-s));
            } else if (ACT == 3) {
                float g = 1.f / (1.f + expf(-s));
                Cmat[idx] = g * aux1[idx];
            } else if (ACT == 4) {
                float t = tanhf(s + addmat[idx]);
                float z = aux1[idx];
                float h = aux2[idx];
                Cmat[idx] = (1.f - z) * t + z * h;
            } else { // 5: gate triple
                if (bz == 2) {
                    Cmat[idx] = s;
                } else {
                    float g = 1.f / (1.f + expf(-s));
                    Cmat[idx] = (bz == 1) ? g * aux1[idx] : g;
                }
            }
        }
    }
}

// ---------------------------------------------------------------------------
// out[n,c,t,w] = sum_v relu(h)[n,v,c*T+t] * A_new[n,c,v,w]
// ---------------------------------------------------------------------------
__global__ __launch_bounds__(128) void out_einsum_kernel(
    const float* __restrict__ h, const float* __restrict__ A_new,
    float* __restrict__ out)
{
    __shared__ float hf[12 * 400];
    int c = blockIdx.y, n = blockIdx.z;
    int tid = threadIdx.x;
    for (int q = tid; q < 12 * 400; q += 128) {
        int t = q % 12, v = q / 12;
        float val = h[((long)(n * V_ + v)) * D_ + c * 12 + t];
        hf[t * 400 + v] = fmaxf(val, 0.f);
    }
    __syncthreads();
    int w = blockIdx.x * 128 + tid;
    if (w >= V_) return;
    float acc[12] = {};
    const float* Ap = A_new + ((long)(n * C_ + c) * V_) * V_ + w;
#pragma unroll 4
    for (int v = 0; v < V_; v++) {
        float aw = Ap[(long)v * V_];
#pragma unroll
        for (int t = 0; t < 12; t++) acc[t] = fmaf(hf[t * 400 + v], aw, acc[t]);
    }
    long ob = ((long)(n * C_ + c) * 12) * V_ + w;
#pragma unroll
    for (int t = 0; t < 12; t++) out[ob + (long)t * V_] = acc[t];
}

// ---------------------------------------------------------------------------
extern "C" void kernel_launch(void* const* d_in, const int* in_sizes, int n_in,
                              void* d_out, int out_size, void* d_ws, size_t ws_size,
                              hipStream_t stream)
{
    const float* x    = (const float*)d_in[0];
    const float* A    = (const float*)d_in[1];
    const float* We1  = (const float*)d_in[2];
    const float* be1  = (const float*)d_in[3];
    const float* We2  = (const float*)d_in[4];
    const float* be2  = (const float*)d_in[5];
    const float* We3  = (const float*)d_in[6];
    const float* be3  = (const float*)d_in[7];
    const float* Wn1  = (const float*)d_in[8];
    const float* bn1  = (const float*)d_in[9];
    const float* Wn2  = (const float*)d_in[10];
    const float* bn2  = (const float*)d_in[11];
    const float* Wn3  = (const float*)d_in[12];
    const float* bn3  = (const float*)d_in[13];
    const float* Wmsg = (const float*)d_in[14];
    const float* Wz   = (const float*)d_in[15];
    const float* Uz   = (const float*)d_in[16];
    const float* bz   = (const float*)d_in[17];
    const float* Wr   = (const float*)d_in[18];
    const float* Ur   = (const float*)d_in[19];
    const float* br   = (const float*)d_in[20];
    const float* Wh   = (const float*)d_in[21];
    const float* Uh   = (const float*)d_in[22];
    const float* bh   = (const float*)d_in[23];

    float* out   = (float*)d_out;
    float* A_new = out + (long)N_ * C_ * T_ * V_;   // out is 2457600 floats, then A_new

    float* ws  = (float*)d_ws;
    float* xT  = ws;  ws += NVD;
    float* h   = ws;  ws += NVD;
    float* hm  = ws;  ws += NVD;   // also reused as mWh after mb is formed
    float* mb  = ws;  ws += NVD;
    float* zg  = ws;  ws += NVD;
    float* rh  = ws;  ws += NVD;
    float* Y1  = ws;  ws += NVH;
    float* Y2  = ws;  ws += NVH;
    float* As_ = ws;  ws += NVV;

    transpose_x_kernel<<<dim3(13, 24, 8), 256, 0, stream>>>(x, xT);
    edge_mlp_kernel<<<dim3(2, 400, 8), 256, 0, stream>>>(A, We1, be1, We2, be2, We3, be3,
                                                         A_new, As_);
    // node MLP: 768 -> 96 -> 96 -> 768
    gemm_kernel<1, false><<<dim3(25, 2, 1), 256, 0, stream>>>(
        xT, 768, Wn1, 96, 768, nullptr, 0, nullptr, 0, 0,
        bn1, Y1, 96, nullptr, nullptr, 3200, 96, 0, 0, 0,
        nullptr, nullptr, nullptr, nullptr, nullptr, nullptr, nullptr, nullptr);
    gemm_kernel<1, false><<<dim3(25, 2, 1), 256, 0, stream>>>(
        Y1, 96, Wn2, 96, 96, nullptr, 0, nullptr, 0, 0,
        bn2, Y2, 96, nullptr, nullptr, 3200, 96, 0, 0, 0,
        nullptr, nullptr, nullptr, nullptr, nullptr, nullptr, nullptr, nullptr);
    gemm_kernel<0, false><<<dim3(25, 12, 1), 256, 0, stream>>>(
        Y2, 96, Wn3, 768, 96, nullptr, 0, nullptr, 0, 0,
        bn3, h, 768, nullptr, nullptr, 3200, 768, 0, 0, 0,
        nullptr, nullptr, nullptr, nullptr, nullptr, nullptr, nullptr, nullptr);

    for (int it = 0; it < 2; ++it) {
        // hm = h @ Wmsg
        gemm_kernel<0, false><<<dim3(25, 12, 1), 256, 0, stream>>>(
            h, 768, Wmsg, 768, 768, nullptr, 0, nullptr, 0, 0,
            nullptr, hm, 768, nullptr, nullptr, 3200, 768, 0, 0, 0,
            nullptr, nullptr, nullptr, nullptr, nullptr, nullptr, nullptr, nullptr);
        // m[n] = A_s[n] @ hm[n]   (batched over n)
        gemm_kernel<0, false><<<dim3(4, 12, 8), 256, 0, stream>>>(
            As_, 400, hm, 768, 400, nullptr, 0, nullptr, 0, 0,
            nullptr, mb, 768, nullptr, nullptr, 400, 768,
            (long)VV, (long)V_ * D_, (long)V_ * D_,
            nullptr, nullptr, nullptr, nullptr, nullptr, nullptr, nullptr, nullptr);
        // ONE launch, z in {0,1,2}:
        //   z=0: zg  = sigmoid(m@Wz + h@Uz + bz)
        //   z=1: rh  = sigmoid(m@Wr + h@Ur + br) * h
        //   z=2: mWh = m@Wh + bh              (stored into hm, which is free now)
        gemm_kernel<5, true><<<dim3(25, 12, 3), 256, 0, stream>>>(
            mb, 768, Wz, 768, 768, h, 768, Uz, 768, 768,
            bz, zg, 768, h, nullptr, 3200, 768, 0, 0, 0,
            Wr, Ur, br, rh, Wh, bh, hm, nullptr);
        // h = (1-zg)*tanh(rh@Uh + mWh) + zg*h     (mWh already contains bh)
        gemm_kernel<4, false><<<dim3(25, 12, 1), 256, 0, stream>>>(
            rh, 768, Uh, 768, 768, nullptr, 0, nullptr, 0, 0,
            nullptr, h, 768, zg, h, 3200, 768, 0, 0, 0,
            nullptr, nullptr, nullptr, nullptr, nullptr, nullptr, nullptr, hm);
    }

    out_einsum_kernel<<<dim3(4, 64, 8), 128, 0, stream>>>(h, A_new, out);
}

// Round 12
// 1202.170 us; speedup vs baseline: 1.4798x; 1.4798x over previous
//
#include <hip/hip_runtime.h>
#include <math.h>

#define N_ 8
#define C_ 64
#define T_ 12
#define V_ 400
#define D_ 768
#define HN_ 96
#define VV 160000          // V*V
#define NVD 2457600        // N*V*D
#define NVH 307200         // N*V*HN
#define NVV 1280000        // N*V*V
#define WSZ 589824         // 768*768

typedef float f32x4 __attribute__((ext_vector_type(4)));
typedef __bf16 bf16x8 __attribute__((ext_vector_type(8)));

__device__ __forceinline__ unsigned short f2bf(float f) {
    unsigned int u = __float_as_uint(f);
    u = (u + 0x7FFFu + ((u >> 16) & 1u)) >> 16;
    return (unsigned short)u;
}

// ---------------------------------------------------------------------------
// Transpose x [8,768,400] -> xT [8,400,768]
// ---------------------------------------------------------------------------
__global__ __launch_bounds__(256) void transpose_x_kernel(
    const float* __restrict__ x, float* __restrict__ xT)
{
    __shared__ float tile[32][33];
    int n  = blockIdx.z;
    int d0 = blockIdx.y * 32;
    int v0 = blockIdx.x * 32;
    int tx = threadIdx.x & 31, ty = threadIdx.x >> 5;
#pragma unroll
    for (int r = 0; r < 4; r++) {
        int d = d0 + ty + r * 8;
        int v = v0 + tx;
        float val = (v < V_) ? x[((long)n * D_ + d) * V_ + v] : 0.f;
        tile[ty + r * 8][tx] = val;
    }
    __syncthreads();
#pragma unroll
    for (int r = 0; r < 4; r++) {
        int v = v0 + ty + r * 8;
        int d = d0 + tx;
        if (v < V_) xT[((long)n * V_ + v) * D_ + d] = tile[tx][ty + r * 8];
    }
}

// ---------------------------------------------------------------------------
// Weight convert+transpose: 7x [768][768] f32 -> [768][768] bf16 (as [N][K])
// ---------------------------------------------------------------------------
struct WP { const float* p[7]; };

__global__ __launch_bounds__(256) void wconv_kernel(WP wp, unsigned short* __restrict__ dst)
{
    __shared__ float t[32][33];
    const float* src = wp.p[blockIdx.z];
    unsigned short* d = dst + (long)blockIdx.z * WSZ;
    int k0 = blockIdx.y * 32, n0 = blockIdx.x * 32;
    int tx = threadIdx.x & 31, ty = threadIdx.x >> 5;
#pragma unroll
    for (int r = 0; r < 4; r++)
        t[ty + r * 8][tx] = src[(long)(k0 + ty + r * 8) * D_ + n0 + tx];
    __syncthreads();
#pragma unroll
    for (int r = 0; r < 4; r++)
        d[(long)(n0 + ty + r * 8) * D_ + k0 + tx] = f2bf(t[tx][ty + r * 8]);
}

// ---------------------------------------------------------------------------
// Edge MLP: A[8,8,400,400] -> A_new[8,64,400,400] (masked) + A_s[8,400,400]
// ---------------------------------------------------------------------------
__global__ __launch_bounds__(256) void edge_mlp_kernel(
    const float* __restrict__ A,
    const float* __restrict__ We1, const float* __restrict__ be1,
    const float* __restrict__ We2, const float* __restrict__ be2,
    const float* __restrict__ We3, const float* __restrict__ be3,
    float* __restrict__ A_new, float* __restrict__ A_s)
{
    __shared__ float w1[7 * 14], b1[14], w2[14 * 14], b2[14], w3[14 * 64], b3[64];
    int tid = threadIdx.x;
    for (int i = tid; i < 98;  i += 256) w1[i] = We1[i];
    for (int i = tid; i < 196; i += 256) w2[i] = We2[i];
    for (int i = tid; i < 896; i += 256) w3[i] = We3[i];
    for (int i = tid; i < 14;  i += 256) { b1[i] = be1[i]; b2[i] = be2[i]; }
    for (int i = tid; i < 64;  i += 256) b3[i] = be3[i];
    __syncthreads();

    int j = blockIdx.x * 256 + tid;
    if (j >= V_) return;
    int i_ = blockIdx.y;
    int n  = blockIdx.z;

    long base = ((long)(n * 8) * V_ + i_) * V_ + j;
    float feat[7];
#pragma unroll
    for (int k = 0; k < 7; k++) feat[k] = A[base + (long)k * VV];
    float mk = (A[base + 7L * VV] > 0.5f) ? 1.0f : 0.0f;

    float e1[14];
#pragma unroll
    for (int l = 0; l < 14; l++) {
        float s = b1[l];
#pragma unroll
        for (int k = 0; k < 7; k++) s = fmaf(feat[k], w1[k * 14 + l], s);
        e1[l] = fmaxf(s, 0.f);
    }
    float e2[14];
#pragma unroll
    for (int l = 0; l < 14; l++) {
        float s = b2[l];
#pragma unroll
        for (int k = 0; k < 14; k++) s = fmaf(e1[k], w2[k * 14 + l], s);
        e2[l] = fmaxf(s, 0.f);
    }

    long obase = ((long)(n * C_) * V_ + i_) * V_ + j;
    float sum = 0.f;
#pragma unroll
    for (int c = 0; c < 64; c++) {
        float s = b3[c];
#pragma unroll
        for (int l = 0; l < 14; l++) s = fmaf(e2[l], w3[l * 64 + c], s);
        s *= mk;
        A_new[obase + (long)c * VV] = s;
        sum += s;
    }
    A_s[((long)n * V_ + i_) * V_ + j] = sum * (1.0f / 64.0f);
}

// ---------------------------------------------------------------------------
// fp32 vector GEMM (node MLP + batched A_s@hm). ACT: 0 none, 1 relu.
// BM=128, BN=64, BK=16, 256 threads, 8x4 per thread.
// ---------------------------------------------------------------------------
template <int ACT>
__global__ __launch_bounds__(256) void gemm_kernel(
    const float* __restrict__ A1, int lda1, const float* __restrict__ B1, int ldb1, int K1,
    const float* __restrict__ bias, float* __restrict__ Cmat, int ldc,
    int M, int Ncols, long batchA, long batchB, long batchC)
{
    __shared__ float As[16][132];
    __shared__ float Bs[16][68];
    const int tid = threadIdx.x;
    const int tx = tid & 15;
    const int ty = tid >> 4;
    const int row0 = blockIdx.x * 128;
    const int col0 = blockIdx.y * 64;
    const int bz = blockIdx.z;
    A1 += (long)bz * batchA;
    B1 += (long)bz * batchB;
    Cmat += (long)bz * batchC;

    float acc[8][4];
#pragma unroll
    for (int i = 0; i < 8; i++)
#pragma unroll
        for (int j = 0; j < 4; j++) acc[i][j] = 0.f;

    for (int k0 = 0; k0 < K1; k0 += 16) {
#pragma unroll
        for (int l = 0; l < 2; l++) {
            int idx = tid + l * 256;
            int row = idx >> 2;
            int kk  = (idx & 3) * 4;
            float4 v = make_float4(0.f, 0.f, 0.f, 0.f);
            if (row0 + row < M)
                v = *reinterpret_cast<const float4*>(A1 + (long)(row0 + row) * lda1 + k0 + kk);
            As[kk + 0][row] = v.x;
            As[kk + 1][row] = v.y;
            As[kk + 2][row] = v.z;
            As[kk + 3][row] = v.w;
        }
        {
            int k  = tid >> 4;
            int nn = (tid & 15) * 4;
            float4 v = make_float4(0.f, 0.f, 0.f, 0.f);
            if (col0 + nn < Ncols)
                v = *reinterpret_cast<const float4*>(B1 + (long)(k0 + k) * ldb1 + col0 + nn);
            *reinterpret_cast<float4*>(&Bs[k][nn]) = v;
        }
        __syncthreads();
#pragma unroll
        for (int kk = 0; kk < 16; kk++) {
            float4 a0 = *reinterpret_cast<const float4*>(&As[kk][ty * 4]);
            float4 a1 = *reinterpret_cast<const float4*>(&As[kk][ty * 4 + 64]);
            float4 b0 = *reinterpret_cast<const float4*>(&Bs[kk][tx * 4]);
            float a[8] = {a0.x, a0.y, a0.z, a0.w, a1.x, a1.y, a1.z, a1.w};
            float b[4] = {b0.x, b0.y, b0.z, b0.w};
#pragma unroll
            for (int i = 0; i < 8; i++)
#pragma unroll
                for (int j = 0; j < 4; j++)
                    acc[i][j] = fmaf(a[i], b[j], acc[i][j]);
        }
        __syncthreads();
    }

#pragma unroll
    for (int i = 0; i < 8; i++) {
        int r = row0 + ((i < 4) ? (ty * 4 + i) : (64 + ty * 4 + i - 4));
        if (r >= M) continue;
#pragma unroll
        for (int j = 0; j < 4; j++) {
            int c = col0 + tx * 4 + j;
            if (c >= Ncols) continue;
            float s = acc[i][j];
            if (bias) s += bias[c];
            long idx = (long)r * ldc + c;
            if (ACT == 1) s = fmaxf(s, 0.f);
            Cmat[idx] = s;
        }
    }
}

// ---------------------------------------------------------------------------
// bf16 MFMA GEMM: M=3200, N=768, K=768 fixed. fp32 in (converted in staging),
// bf16 [N][K] weights, fp32 out. BM=128, BN=64, BK=32, 4 waves (2x2), 64x32/wave.
// ACT: 0 none (+opt bias), 4 GRU update, 5 gate-triple via blockIdx.z.
// ---------------------------------------------------------------------------
template <int ACT>
__global__ __launch_bounds__(256) void mgemm_kernel(
    const float* __restrict__ A1, const unsigned short* __restrict__ B1,
    const float* __restrict__ A2, const unsigned short* __restrict__ B2, int K2,
    const float* __restrict__ bias, float* __restrict__ Cmat,
    const float* __restrict__ aux1, const float* __restrict__ aux2,
    const float* __restrict__ addmat,
    const unsigned short* __restrict__ B1r, const unsigned short* __restrict__ B2r,
    const float* __restrict__ biasr, float* __restrict__ Cr,
    const unsigned short* __restrict__ B1h, const float* __restrict__ biash,
    float* __restrict__ Ch)
{
    __shared__ unsigned short sA[128 * 36];
    __shared__ unsigned short sB[64 * 36];

    const int tid  = threadIdx.x;
    const int l    = tid & 63;
    const int wave = tid >> 6;
    const int wr   = wave >> 1;       // 0..1, M-half
    const int wc   = wave & 1;        // 0..1, N-half
    const int lrow = l & 15;
    const int g    = l >> 4;          // 0..3
    const int row0 = blockIdx.x * 128;
    const int col0 = blockIdx.y * 64;
    const int bz   = blockIdx.z;

    if (ACT == 5) {
        if (bz == 1)      { B1 = B1r; B2 = B2r; bias = biasr; Cmat = Cr; }
        else if (bz == 2) { B1 = B1h; K2 = 0;   bias = biash; Cmat = Ch; }
    }

    f32x4 acc[4][2];
#pragma unroll
    for (int mi = 0; mi < 4; mi++)
#pragma unroll
        for (int ni = 0; ni < 2; ni++) acc[mi][ni] = (f32x4)0.f;

    for (int ph = 0; ph < 2; ph++) {
        if (ph == 1 && K2 == 0) break;
        const float* Ap = ph ? A2 : A1;
        const unsigned short* Bp = ph ? B2 : B1;
        for (int k0 = 0; k0 < D_; k0 += 32) {
            // stage A: 128x32 f32 -> bf16, ld 36
#pragma unroll
            for (int i = 0; i < 4; i++) {
                int u   = i * 256 + tid;
                int row = u >> 3;
                int kq  = u & 7;
                float4 v = *reinterpret_cast<const float4*>(Ap + (long)(row0 + row) * D_ + k0 + kq * 4);
                ushort4 b;
                b.x = f2bf(v.x); b.y = f2bf(v.y); b.z = f2bf(v.z); b.w = f2bf(v.w);
                *reinterpret_cast<ushort4*>(&sA[row * 36 + kq * 4]) = b;
            }
            // stage B: 64x32 bf16 from [N][K], ld 36
            {
                int row = tid >> 2;
                int kq  = tid & 3;          // 8-elem chunk
                union { uint4 q; unsigned long long d[2]; } u;
                u.q = *reinterpret_cast<const uint4*>(Bp + (long)(col0 + row) * D_ + k0 + kq * 8);
                *reinterpret_cast<unsigned long long*>(&sB[row * 36 + kq * 8])     = u.d[0];
                *reinterpret_cast<unsigned long long*>(&sB[row * 36 + kq * 8 + 4]) = u.d[1];
            }
            __syncthreads();

            union FR { unsigned long long q[2]; bf16x8 v; };
            FR bfr[2];
#pragma unroll
            for (int ni = 0; ni < 2; ni++) {
                int off = (wc * 32 + ni * 16 + lrow) * 36 + g * 4;
                bfr[ni].q[0] = *reinterpret_cast<const unsigned long long*>(&sB[off]);
                bfr[ni].q[1] = *reinterpret_cast<const unsigned long long*>(&sB[off + 16]);
            }
#pragma unroll
            for (int mi = 0; mi < 4; mi++) {
                FR afr;
                int off = (wr * 64 + mi * 16 + lrow) * 36 + g * 4;
                afr.q[0] = *reinterpret_cast<const unsigned long long*>(&sA[off]);
                afr.q[1] = *reinterpret_cast<const unsigned long long*>(&sA[off + 16]);
#pragma unroll
                for (int ni = 0; ni < 2; ni++)
                    acc[mi][ni] = __builtin_amdgcn_mfma_f32_16x16x32_bf16(
                        afr.v, bfr[ni].v, acc[mi][ni], 0, 0, 0);
            }
            __syncthreads();
        }
    }

#pragma unroll
    for (int mi = 0; mi < 4; mi++)
#pragma unroll
    for (int ni = 0; ni < 2; ni++) {
        int cc = col0 + wc * 32 + ni * 16 + lrow;
        int rb = row0 + wr * 64 + mi * 16 + g * 4;
        float bv = bias ? bias[cc] : 0.f;
#pragma unroll
        for (int rg = 0; rg < 4; rg++) {
            long idx = (long)(rb + rg) * D_ + cc;
            float s = acc[mi][ni][rg] + bv;
            if (ACT == 0) {
                Cmat[idx] = s;
            } else if (ACT == 4) {
                float t = tanhf(s + addmat[idx]);
                float z = aux1[idx];
                float ho = aux2[idx];
                Cmat[idx] = (1.f - z) * t + z * ho;
            } else { // 5
                if (bz == 2) {
                    Cmat[idx] = s;
                } else {
                    float gg = 1.f / (1.f + expf(-s));
                    Cmat[idx] = (bz == 1) ? gg * aux1[idx] : gg;
                }
            }
        }
    }
}

// ---------------------------------------------------------------------------
// out[n,c,t,w] = sum_v relu(h)[n,v,c*T+t] * A_new[n,c,v,w]
// ---------------------------------------------------------------------------
__global__ __launch_bounds__(128) void out_einsum_kernel(
    const float* __restrict__ h, const float* __restrict__ A_new,
    float* __restrict__ out)
{
    __shared__ float hf[12 * 400];
    int c = blockIdx.y, n = blockIdx.z;
    int tid = threadIdx.x;
    for (int q = tid; q < 12 * 400; q += 128) {
        int t = q % 12, v = q / 12;
        float val = h[((long)(n * V_ + v)) * D_ + c * 12 + t];
        hf[t * 400 + v] = fmaxf(val, 0.f);
    }
    __syncthreads();
    int w = blockIdx.x * 128 + tid;
    if (w >= V_) return;
    float acc[12] = {};
    const float* Ap = A_new + ((long)(n * C_ + c) * V_) * V_ + w;
#pragma unroll 4
    for (int v = 0; v < V_; v++) {
        float aw = Ap[(long)v * V_];
#pragma unroll
        for (int t = 0; t < 12; t++) acc[t] = fmaf(hf[t * 400 + v], aw, acc[t]);
    }
    long ob = ((long)(n * C_ + c) * 12) * V_ + w;
#pragma unroll
    for (int t = 0; t < 12; t++) out[ob + (long)t * V_] = acc[t];
}

// ---------------------------------------------------------------------------
extern "C" void kernel_launch(void* const* d_in, const int* in_sizes, int n_in,
                              void* d_out, int out_size, void* d_ws, size_t ws_size,
                              hipStream_t stream)
{
    const float* x    = (const float*)d_in[0];
    const float* A    = (const float*)d_in[1];
    const float* We1  = (const float*)d_in[2];
    const float* be1  = (const float*)d_in[3];
    const float* We2  = (const float*)d_in[4];
    const float* be2  = (const float*)d_in[5];
    const float* We3  = (const float*)d_in[6];
    const float* be3  = (const float*)d_in[7];
    const float* Wn1  = (const float*)d_in[8];
    const float* bn1  = (const float*)d_in[9];
    const float* Wn2  = (const float*)d_in[10];
    const float* bn2  = (const float*)d_in[11];
    const float* Wn3  = (const float*)d_in[12];
    const float* bn3  = (const float*)d_in[13];
    const float* Wmsg = (const float*)d_in[14];
    const float* Wz   = (const float*)d_in[15];
    const float* Uz   = (const float*)d_in[16];
    const float* bz   = (const float*)d_in[17];
    const float* Wr   = (const float*)d_in[18];
    const float* Ur   = (const float*)d_in[19];
    const float* br   = (const float*)d_in[20];
    const float* Wh   = (const float*)d_in[21];
    const float* Uh   = (const float*)d_in[22];
    const float* bh   = (const float*)d_in[23];

    float* out   = (float*)d_out;
    float* A_new = out + (long)N_ * C_ * T_ * V_;

    // bf16 weights first (even element count keeps float alignment after)
    unsigned short* wbf = (unsigned short*)d_ws;        // 7 * 589824 ushorts
    float* ws  = (float*)(wbf + 7L * WSZ);
    float* xT  = ws;  ws += NVD;
    float* h   = ws;  ws += NVD;
    float* hm  = ws;  ws += NVD;   // reused as mWh inside GGC layer
    float* mb  = ws;  ws += NVD;
    float* zg  = ws;  ws += NVD;
    float* rh  = ws;  ws += NVD;
    float* Y1  = ws;  ws += NVH;
    float* Y2  = ws;  ws += NVH;
    float* As_ = ws;  ws += NVV;

    const unsigned short* WmsgB = wbf + 0L * WSZ;
    const unsigned short* WzB   = wbf + 1L * WSZ;
    const unsigned short* UzB   = wbf + 2L * WSZ;
    const unsigned short* WrB   = wbf + 3L * WSZ;
    const unsigned short* UrB   = wbf + 4L * WSZ;
    const unsigned short* WhB   = wbf + 5L * WSZ;
    const unsigned short* UhB   = wbf + 6L * WSZ;

    transpose_x_kernel<<<dim3(13, 24, 8), 256, 0, stream>>>(x, xT);

    WP wp;
    wp.p[0] = Wmsg; wp.p[1] = Wz; wp.p[2] = Uz; wp.p[3] = Wr;
    wp.p[4] = Ur;   wp.p[5] = Wh; wp.p[6] = Uh;
    wconv_kernel<<<dim3(24, 24, 7), 256, 0, stream>>>(wp, wbf);

    edge_mlp_kernel<<<dim3(2, 400, 8), 256, 0, stream>>>(A, We1, be1, We2, be2, We3, be3,
                                                         A_new, As_);
    // node MLP: 768 -> 96 -> 96 -> 768 (fp32 vector)
    gemm_kernel<1><<<dim3(25, 2, 1), 256, 0, stream>>>(
        xT, 768, Wn1, 96, 768, bn1, Y1, 96, 3200, 96, 0, 0, 0);
    gemm_kernel<1><<<dim3(25, 2, 1), 256, 0, stream>>>(
        Y1, 96, Wn2, 96, 96, bn2, Y2, 96, 3200, 96, 0, 0, 0);
    gemm_kernel<0><<<dim3(25, 12, 1), 256, 0, stream>>>(
        Y2, 96, Wn3, 768, 96, bn3, h, 768, 3200, 768, 0, 0, 0);

    for (int it = 0; it < 2; ++it) {
        // hm = h @ Wmsg   (bf16 MFMA)
        mgemm_kernel<0><<<dim3(25, 12, 1), 256, 0, stream>>>(
            h, WmsgB, nullptr, nullptr, 0, nullptr, hm,
            nullptr, nullptr, nullptr,
            nullptr, nullptr, nullptr, nullptr, nullptr, nullptr, nullptr);
        // mb[n] = A_s[n] @ hm[n]   (fp32 vector, batched over n)
        gemm_kernel<0><<<dim3(4, 12, 8), 256, 0, stream>>>(
            As_, 400, hm, 768, 400, nullptr, mb, 768, 400, 768,
            (long)VV, (long)V_ * D_, (long)V_ * D_);
        // gate triple (bf16 MFMA), z in {0,1,2}:
        //   z=0: zg  = sigmoid(mb@Wz + h@Uz + bz)
        //   z=1: rh  = sigmoid(mb@Wr + h@Ur + br) * h
        //   z=2: mWh = mb@Wh + bh  -> hm
        mgemm_kernel<5><<<dim3(25, 12, 3), 256, 0, stream>>>(
            mb, WzB, h, UzB, 768, bz, zg,
            h, nullptr, nullptr,
            WrB, UrB, br, rh, WhB, bh, hm);
        // h = (1-zg)*tanh(rh@Uh + mWh) + zg*h   (bf16 MFMA)
        mgemm_kernel<4><<<dim3(25, 12, 1), 256, 0, stream>>>(
            rh, UhB, nullptr, nullptr, 0, nullptr, h,
            zg, h, hm,
            nullptr, nullptr, nullptr, nullptr, nullptr, nullptr, nullptr);
    }

    out_einsum_kernel<<<dim3(4, 64, 8), 128, 0, stream>>>(h, A_new, out);
}